// Round 11
// baseline (81.826 us; speedup 1.0000x reference)
//
#include <hip/hip_runtime.h>
#include <hip/hip_bf16.h>

#define NOUT 7
#define NBIN 49
#define NCH 256

typedef unsigned short ushort4_t __attribute__((ext_vector_type(4)));
typedef float float4_t __attribute__((ext_vector_type(4)));

__device__ inline float bflo(unsigned int u) { return __uint_as_float(u << 16); }
__device__ inline float bfhi(unsigned int u) { return __uint_as_float(u & 0xffff0000u); }
__device__ inline float bf2f(unsigned short u) { return __uint_as_float(((unsigned int)u) << 16); }
__device__ inline unsigned short f2bf(float f) {
    __hip_bfloat16 h = __float2bfloat16(f);
    return *reinterpret_cast<unsigned short*>(&h);
}
__device__ inline unsigned int pack2(float lo, float hi) {
    return (unsigned int)f2bf(lo) | ((unsigned int)f2bf(hi) << 16);
}

// ---------- merged NCHW f32 -> NHWC bf16 transpose, full-row wave stores ----------
// block: 64 p x 256 c. Write side: lane l stores channels 8l..8l+7 (16B uint4);
// one wave instruction covers TWO complete 512B NHWC rows (no sibling timing needed).
// LDS: u32[128 cpair][65 p] packed bf16 pairs, 33.3 KB -> 4 blocks/CU.
// Read side unchanged vs R10: float4 along p, 256B/channel segments.
// level p-tiles x batches: l0 950*2, l1 238*2, l2 60*2, l3 15*2 => 2526 blocks
__global__ __launch_bounds__(256) void transpose_all_kernel(
    const float* __restrict__ f0, const float* __restrict__ f1,
    const float* __restrict__ f2, const float* __restrict__ f3,
    unsigned short* __restrict__ ws)
{
    __shared__ unsigned int lt[128 * 65];   // [cpair][p], stride 65 (2-way free on write side)

    int bid = blockIdx.x;
    const float* in;
    unsigned short* out;
    int HW, npt;
    if (bid < 1900)      { in = f0; out = ws;            HW = 60800; npt = 950; }
    else if (bid < 2376) { in = f1; out = ws + 31129600; HW = 15200; npt = 238; bid -= 1900; }
    else if (bid < 2496) { in = f2; out = ws + 38912000; HW = 3800;  npt = 60;  bid -= 2376; }
    else                 { in = f3; out = ws + 40857600; HW = 950;   npt = 15;  bid -= 2496; }

    const int p0 = (bid % npt) << 6;
    const int b  = bid / npt;
    const int t  = threadIdx.x;

    // ---- read phase: thread = (p-quad, channel-pair); float4 along p ----
    const int pq = (t & 15) << 2;          // p offset 0..60
    const size_t inb = (size_t)b * NCH * (size_t)HW;
    #pragma unroll
    for (int pass = 0; pass < 8; ++pass) {
        const int cp = pass * 16 + (t >> 4);   // 0..127
        const int c  = cp * 2;
        const int gp = p0 + pq;
        const float* s0 = in + inb + (size_t)c * HW + gp;
        const float* s1 = s0 + HW;
        unsigned int* dst = &lt[cp * 65 + pq];
        if (gp + 3 < HW) {
            const float4 a = *(const float4*)s0;
            const float4 v = *(const float4*)s1;
            dst[0] = pack2(a.x, v.x);
            dst[1] = pack2(a.y, v.y);
            dst[2] = pack2(a.z, v.z);
            dst[3] = pack2(a.w, v.w);
        } else {
            #pragma unroll
            for (int j = 0; j < 4; ++j)
                if (gp + j < HW) dst[j] = pack2(s0[j], s1[j]);
        }
    }
    __syncthreads();

    // ---- write phase: lane l -> channels 8l..8l+7, 16B store; wave = 2 full rows ----
    const size_t outb = (size_t)b * (size_t)HW * NCH;
    const int l = t & 31;
    #pragma unroll
    for (int pass = 0; pass < 8; ++pass) {
        const int pr = pass * 8 + (t >> 5);   // 0..63
        if (p0 + pr < HW) {
            uint4 v;
            v.x = lt[(4 * l + 0) * 65 + pr];
            v.y = lt[(4 * l + 1) * 65 + pr];
            v.z = lt[(4 * l + 2) * 65 + pr];
            v.w = lt[(4 * l + 3) * 65 + pr];
            *(uint4*)(out + outb + (size_t)(p0 + pr) * NCH + 8 * l) = v;
        }
    }
}

// ---------- pooling from NHWC bf16: 2 blocks/box (128 ch), 2 bins/wave, nt stores ----------
__global__ __launch_bounds__(256) void pool_nhwc_kernel(
    const unsigned short* __restrict__ ws, const float* __restrict__ boxes,
    const int* __restrict__ bidx, float* __restrict__ out, int nbox)
{
    __shared__ unsigned short so[NBIN * 132];   // [bin][c_local], bf16, 12.9 KB

    const int n = blockIdx.x;
    if (n >= nbox) return;
    const int chalf = blockIdx.y << 7;          // 0 or 128
    const int lane = threadIdx.x & 63;
    const int wave = threadIdx.x >> 6;

    const float bx1 = boxes[4*n+0];
    const float by1 = boxes[4*n+1];
    const float bx2 = boxes[4*n+2];
    const float by2 = boxes[4*n+3];

    const float wwb = bx2 - bx1 + 1.0f;
    const float hhb = by2 - by1 + 1.0f;
    const float s  = sqrtf(wwb * hhb);
    int lvl = (int)floorf(4.0f + log2f(1e-6f + s * (1.0f / 224.0f)));
    lvl = min(max(lvl, 2), 5) - 2;

    int H, W;
    float scale;
    size_t off;
    if (lvl == 0)      { H = 200; W = 304; scale = 0.25f;    off = 0;        }
    else if (lvl == 1) { H = 100; W = 152; scale = 0.125f;   off = 31129600; }
    else if (lvl == 2) { H = 50;  W = 76;  scale = 0.0625f;  off = 38912000; }
    else               { H = 25;  W = 38;  scale = 0.03125f; off = 40857600; }

    const int b = bidx[n];
    const int cloc = (lane & 31) * 4;           // local channel (0..124)
    const unsigned short* __restrict__ fb =
        ws + off + (size_t)b * (size_t)(H * W) * NCH + chalf + cloc;

    const float x1 = bx1 * scale;
    const float y1 = by1 * scale;
    const float x2 = bx2 * scale;
    const float y2 = by2 * scale;
    const float roi_w = fmaxf(x2 - x1, 1.0f);
    const float roi_h = fmaxf(y2 - y1, 1.0f);
    const float bw = roi_w * (1.0f / NOUT);
    const float bh = roi_h * (1.0f / NOUT);

    const float Hf = (float)H, Wf = (float)W;

    // wave w covers bin pairs {2w, 2w+1} stepping by 8; half-wave picks the pair element
    for (int eb = wave * 2; eb < NBIN; eb += 8) {
        const int e = eb + (lane >> 5);
        const bool evalid = (e < NBIN);
        const int ec = evalid ? e : 0;
        const int py = ec / NOUT;
        const int px = ec - py * NOUT;
        float a0 = 0.0f, a1 = 0.0f, a2 = 0.0f, a3 = 0.0f;
        #pragma unroll
        for (int iy = 0; iy < 2; ++iy) {
            #pragma unroll
            for (int ix = 0; ix < 2; ++ix) {
                float y = y1 + ((float)py + 0.25f + 0.5f * (float)iy) * bh;
                float x = x1 + ((float)px + 0.25f + 0.5f * (float)ix) * bw;
                const bool valid = (y >= -1.0f) && (y <= Hf) && (x >= -1.0f) && (x <= Wf);
                y = fminf(fmaxf(y, 0.0f), Hf - 1.0f);
                x = fminf(fmaxf(x, 0.0f), Wf - 1.0f);
                const int y0 = (int)floorf(y);
                const int x0 = (int)floorf(x);
                const int y1i = min(y0 + 1, H - 1);
                const int x1i = min(x0 + 1, W - 1);
                const float ly = y - (float)y0;
                const float lx = x - (float)x0;
                const float hy = 1.0f - ly;
                const float hx = 1.0f - lx;
                const float w00 = hy * hx, w01 = hy * lx, w10 = ly * hx, w11 = ly * lx;

                const uint2 u00 = *(const uint2*)(fb + (unsigned)(y0  * W + x0 ) * NCH);
                const uint2 u01 = *(const uint2*)(fb + (unsigned)(y0  * W + x1i) * NCH);
                const uint2 u10 = *(const uint2*)(fb + (unsigned)(y1i * W + x0 ) * NCH);
                const uint2 u11 = *(const uint2*)(fb + (unsigned)(y1i * W + x1i) * NCH);

                if (valid) {
                    a0 += w00 * bflo(u00.x) + w01 * bflo(u01.x) + w10 * bflo(u10.x) + w11 * bflo(u11.x);
                    a1 += w00 * bfhi(u00.x) + w01 * bfhi(u01.x) + w10 * bfhi(u10.x) + w11 * bfhi(u11.x);
                    a2 += w00 * bflo(u00.y) + w01 * bflo(u01.y) + w10 * bflo(u10.y) + w11 * bflo(u11.y);
                    a3 += w00 * bfhi(u00.y) + w01 * bfhi(u01.y) + w10 * bfhi(u10.y) + w11 * bfhi(u11.y);
                }
            }
        }
        if (evalid) {
            ushort4_t r;
            r[0] = f2bf(a0 * 0.25f);
            r[1] = f2bf(a1 * 0.25f);
            r[2] = f2bf(a2 * 0.25f);
            r[3] = f2bf(a3 * 0.25f);
            *(ushort4_t*)&so[e * 132 + cloc] = r;
        }
    }
    __syncthreads();

    // write this (box, channel-half): 128*49 f32 contiguous, non-temporal
    float* __restrict__ outn = out + (size_t)n * (NCH * NBIN) + (size_t)chalf * NBIN;
    for (int idx = threadIdx.x; idx < (128 * NBIN) / 4; idx += 256) {
        const int k = idx * 4;
        float4_t r;
        { const int k0 = k;     const int c = k0 / NBIN; r.x = bf2f(so[(k0 - c * NBIN) * 132 + c]); }
        { const int k1 = k + 1; const int c = k1 / NBIN; r.y = bf2f(so[(k1 - c * NBIN) * 132 + c]); }
        { const int k2 = k + 2; const int c = k2 / NBIN; r.z = bf2f(so[(k2 - c * NBIN) * 132 + c]); }
        { const int k3 = k + 3; const int c = k3 / NBIN; r.w = bf2f(so[(k3 - c * NBIN) * 132 + c]); }
        __builtin_nontemporal_store(r, (float4_t*)outn + idx);
    }
}

// ---------------- fallback (round-1 kernel) if ws too small ----------------
__global__ __launch_bounds__(256) void pooler_kernel(
    const float* __restrict__ f0, const float* __restrict__ f1,
    const float* __restrict__ f2, const float* __restrict__ f3,
    const float* __restrict__ boxes, const int* __restrict__ bidx,
    float* __restrict__ out, int nbox)
{
    const int n = blockIdx.x;
    if (n >= nbox) return;
    const int c = threadIdx.x;

    const float bx1 = boxes[4*n+0];
    const float by1 = boxes[4*n+1];
    const float bx2 = boxes[4*n+2];
    const float by2 = boxes[4*n+3];

    const float ww = bx2 - bx1 + 1.0f;
    const float hh = by2 - by1 + 1.0f;
    const float s  = sqrtf(ww * hh);
    int lvl = (int)floorf(4.0f + log2f(1e-6f + s * (1.0f / 224.0f)));
    lvl = min(max(lvl, 2), 5) - 2;

    const float* f;
    int H, W;
    float scale;
    if (lvl == 0)      { f = f0; H = 200; W = 304; scale = 0.25f;    }
    else if (lvl == 1) { f = f1; H = 100; W = 152; scale = 0.125f;   }
    else if (lvl == 2) { f = f2; H = 50;  W = 76;  scale = 0.0625f;  }
    else               { f = f3; H = 25;  W = 38;  scale = 0.03125f; }

    const int b = bidx[n];
    const float* __restrict__ fb = f + ((size_t)b * NCH + c) * (size_t)(H * W);

    const float x1 = bx1 * scale;
    const float y1 = by1 * scale;
    const float x2 = bx2 * scale;
    const float y2 = by2 * scale;
    const float roi_w = fmaxf(x2 - x1, 1.0f);
    const float roi_h = fmaxf(y2 - y1, 1.0f);
    const float bw = roi_w * (1.0f / NOUT);
    const float bh = roi_h * (1.0f / NOUT);

    const float Hf = (float)H, Wf = (float)W;
    float* __restrict__ outc = out + ((size_t)n * NCH + c) * NBIN;

    for (int py = 0; py < NOUT; ++py) {
        for (int px = 0; px < NOUT; ++px) {
            float acc = 0.0f;
            #pragma unroll
            for (int iy = 0; iy < 2; ++iy) {
                #pragma unroll
                for (int ix = 0; ix < 2; ++ix) {
                    float y = y1 + ((float)py + 0.25f + 0.5f * (float)iy) * bh;
                    float x = x1 + ((float)px + 0.25f + 0.5f * (float)ix) * bw;
                    const bool valid = (y >= -1.0f) && (y <= Hf) && (x >= -1.0f) && (x <= Wf);
                    y = fminf(fmaxf(y, 0.0f), Hf - 1.0f);
                    x = fminf(fmaxf(x, 0.0f), Wf - 1.0f);
                    const int y0 = (int)floorf(y);
                    const int x0 = (int)floorf(x);
                    const int y1i = min(y0 + 1, H - 1);
                    const int x1i = min(x0 + 1, W - 1);
                    const float ly = y - (float)y0;
                    const float lx = x - (float)x0;
                    const float hy = 1.0f - ly;
                    const float hx = 1.0f - lx;
                    const float v00 = fb[y0  * W + x0 ];
                    const float v01 = fb[y0  * W + x1i];
                    const float v10 = fb[y1i * W + x0 ];
                    const float v11 = fb[y1i * W + x1i];
                    float v = hy * hx * v00 + hy * lx * v01
                            + ly * hx * v10 + ly * lx * v11;
                    acc += valid ? v : 0.0f;
                }
            }
            outc[py * NOUT + px] = acc * 0.25f;
        }
    }
}

extern "C" void kernel_launch(void* const* d_in, const int* in_sizes, int n_in,
                              void* d_out, int out_size, void* d_ws, size_t ws_size,
                              hipStream_t stream) {
    const float* f0    = (const float*)d_in[0];
    const float* f1    = (const float*)d_in[1];
    const float* f2    = (const float*)d_in[2];
    const float* f3    = (const float*)d_in[3];
    const float* boxes = (const float*)d_in[4];
    const int*   bidx  = (const int*)d_in[5];
    float*       out   = (float*)d_out;

    const int nbox = in_sizes[5];

    const size_t NEED = 41344000ull * sizeof(unsigned short);  // 82.7 MB
    if (ws_size >= NEED) {
        unsigned short* t = (unsigned short*)d_ws;
        transpose_all_kernel<<<2526, 256, 0, stream>>>(f0, f1, f2, f3, t);
        pool_nhwc_kernel<<<dim3(nbox, 2), 256, 0, stream>>>(t, boxes, bidx, out, nbox);
    } else {
        pooler_kernel<<<nbox, 256, 0, stream>>>(f0, f1, f2, f3, boxes, bidx, out, nbox);
    }
}

// Round 12
// 80.861 us; speedup vs baseline: 1.0119x; 1.0119x over previous
//
#include <hip/hip_runtime.h>
#include <hip/hip_bf16.h>

#define NOUT 7
#define NBIN 49
#define NCH 256

typedef unsigned short ushort4_t __attribute__((ext_vector_type(4)));
typedef float float4_t __attribute__((ext_vector_type(4)));

__device__ inline float bflo(unsigned int u) { return __uint_as_float(u << 16); }
__device__ inline float bfhi(unsigned int u) { return __uint_as_float(u & 0xffff0000u); }
__device__ inline float bf2f(unsigned short u) { return __uint_as_float(((unsigned int)u) << 16); }
__device__ inline unsigned short f2bf(float f) {
    __hip_bfloat16 h = __float2bfloat16(f);
    return *reinterpret_cast<unsigned short*>(&h);
}

// ---------- merged NCHW f32 -> NHWC bf16 transpose (R10 body + nt input loads) ----------
// Conflict-free [64][65] scalar-LDS body, dense-sibling order:
// bid = ptile*8 + (b*4 + ctile). Input loads are NON-TEMPORAL: input is
// consumed exactly once per replay; keeping it out of L3 leaves room for ws,
// which the pool re-reads moments later.
// level block counts: l0 950*8=7600, l1 238*8=1904, l2 60*8=480, l3 15*8=120 => 10104
__global__ __launch_bounds__(256) void transpose_all_kernel(
    const float* __restrict__ f0, const float* __restrict__ f1,
    const float* __restrict__ f2, const float* __restrict__ f3,
    unsigned short* __restrict__ ws)
{
    __shared__ float tile[64][65];   // stride 65: writes stride-1, reads conflict-free

    int bid = blockIdx.x;
    const float* in;
    unsigned short* out;
    int HW;
    if (bid < 7600)      { in = f0; out = ws;            HW = 60800; }
    else if (bid < 9504) { in = f1; out = ws + 31129600; HW = 15200; bid -= 7600; }
    else if (bid < 9984) { in = f2; out = ws + 38912000; HW = 3800;  bid -= 9504; }
    else                 { in = f3; out = ws + 40857600; HW = 950;   bid -= 9984; }

    const int combo = bid & 7;         // dense-sibling: combo is the FAST index
    const int p0    = (bid >> 3) << 6;
    const int c0    = (combo & 3) << 6;
    const int b     = combo >> 2;

    const int tp = threadIdx.x & 63;   // p lane (coalesced 256B reads)
    const int tq = threadIdx.x >> 6;   // wave id

    const size_t inb = (size_t)b * NCH * (size_t)HW;
    if (p0 + tp < HW) {
        #pragma unroll
        for (int cc = 0; cc < 64; cc += 4)
            tile[cc + tq][tp] = __builtin_nontemporal_load(
                in + inb + (size_t)(c0 + cc + tq) * HW + (p0 + tp));
    }
    __syncthreads();

    const size_t outb = (size_t)b * (size_t)HW * NCH;
    const int cl = (tp & 31) * 2;        // channel pair
    const int pr = tq * 2 + (tp >> 5);   // p row within each group of 8
    #pragma unroll
    for (int pp = 0; pp < 64; pp += 8) {
        const int p = p0 + pp + pr;
        if (p < HW) {
            __hip_bfloat162 v;
            v.x = __float2bfloat16(tile[cl][pp + pr]);
            v.y = __float2bfloat16(tile[cl + 1][pp + pr]);
            *(__hip_bfloat162*)(out + outb + (size_t)p * NCH + (c0 + cl)) = v;
        }
    }
}

// ---------- pooling from NHWC bf16: 2 blocks/box (128 ch), 2 bins/wave, nt stores ----------
__global__ __launch_bounds__(256) void pool_nhwc_kernel(
    const unsigned short* __restrict__ ws, const float* __restrict__ boxes,
    const int* __restrict__ bidx, float* __restrict__ out, int nbox)
{
    __shared__ unsigned short so[NBIN * 132];   // [bin][c_local], bf16, 12.9 KB

    const int n = blockIdx.x;
    if (n >= nbox) return;
    const int chalf = blockIdx.y << 7;          // 0 or 128
    const int lane = threadIdx.x & 63;
    const int wave = threadIdx.x >> 6;

    const float bx1 = boxes[4*n+0];
    const float by1 = boxes[4*n+1];
    const float bx2 = boxes[4*n+2];
    const float by2 = boxes[4*n+3];

    const float wwb = bx2 - bx1 + 1.0f;
    const float hhb = by2 - by1 + 1.0f;
    const float s  = sqrtf(wwb * hhb);
    int lvl = (int)floorf(4.0f + log2f(1e-6f + s * (1.0f / 224.0f)));
    lvl = min(max(lvl, 2), 5) - 2;

    int H, W;
    float scale;
    size_t off;
    if (lvl == 0)      { H = 200; W = 304; scale = 0.25f;    off = 0;        }
    else if (lvl == 1) { H = 100; W = 152; scale = 0.125f;   off = 31129600; }
    else if (lvl == 2) { H = 50;  W = 76;  scale = 0.0625f;  off = 38912000; }
    else               { H = 25;  W = 38;  scale = 0.03125f; off = 40857600; }

    const int b = bidx[n];
    const int cloc = (lane & 31) * 4;           // local channel (0..124)
    const unsigned short* __restrict__ fb =
        ws + off + (size_t)b * (size_t)(H * W) * NCH + chalf + cloc;

    const float x1 = bx1 * scale;
    const float y1 = by1 * scale;
    const float x2 = bx2 * scale;
    const float y2 = by2 * scale;
    const float roi_w = fmaxf(x2 - x1, 1.0f);
    const float roi_h = fmaxf(y2 - y1, 1.0f);
    const float bw = roi_w * (1.0f / NOUT);
    const float bh = roi_h * (1.0f / NOUT);

    const float Hf = (float)H, Wf = (float)W;

    // wave w covers bin pairs {2w, 2w+1} stepping by 8; half-wave picks the pair element
    for (int eb = wave * 2; eb < NBIN; eb += 8) {
        const int e = eb + (lane >> 5);
        const bool evalid = (e < NBIN);
        const int ec = evalid ? e : 0;
        const int py = ec / NOUT;
        const int px = ec - py * NOUT;
        float a0 = 0.0f, a1 = 0.0f, a2 = 0.0f, a3 = 0.0f;
        #pragma unroll
        for (int iy = 0; iy < 2; ++iy) {
            #pragma unroll
            for (int ix = 0; ix < 2; ++ix) {
                float y = y1 + ((float)py + 0.25f + 0.5f * (float)iy) * bh;
                float x = x1 + ((float)px + 0.25f + 0.5f * (float)ix) * bw;
                const bool valid = (y >= -1.0f) && (y <= Hf) && (x >= -1.0f) && (x <= Wf);
                y = fminf(fmaxf(y, 0.0f), Hf - 1.0f);
                x = fminf(fmaxf(x, 0.0f), Wf - 1.0f);
                const int y0 = (int)floorf(y);
                const int x0 = (int)floorf(x);
                const int y1i = min(y0 + 1, H - 1);
                const int x1i = min(x0 + 1, W - 1);
                const float ly = y - (float)y0;
                const float lx = x - (float)x0;
                const float hy = 1.0f - ly;
                const float hx = 1.0f - lx;
                const float w00 = hy * hx, w01 = hy * lx, w10 = ly * hx, w11 = ly * lx;

                const uint2 u00 = *(const uint2*)(fb + (unsigned)(y0  * W + x0 ) * NCH);
                const uint2 u01 = *(const uint2*)(fb + (unsigned)(y0  * W + x1i) * NCH);
                const uint2 u10 = *(const uint2*)(fb + (unsigned)(y1i * W + x0 ) * NCH);
                const uint2 u11 = *(const uint2*)(fb + (unsigned)(y1i * W + x1i) * NCH);

                if (valid) {
                    a0 += w00 * bflo(u00.x) + w01 * bflo(u01.x) + w10 * bflo(u10.x) + w11 * bflo(u11.x);
                    a1 += w00 * bfhi(u00.x) + w01 * bfhi(u01.x) + w10 * bfhi(u10.x) + w11 * bfhi(u11.x);
                    a2 += w00 * bflo(u00.y) + w01 * bflo(u01.y) + w10 * bflo(u10.y) + w11 * bflo(u11.y);
                    a3 += w00 * bfhi(u00.y) + w01 * bfhi(u01.y) + w10 * bfhi(u10.y) + w11 * bfhi(u11.y);
                }
            }
        }
        if (evalid) {
            ushort4_t r;
            r[0] = f2bf(a0 * 0.25f);
            r[1] = f2bf(a1 * 0.25f);
            r[2] = f2bf(a2 * 0.25f);
            r[3] = f2bf(a3 * 0.25f);
            *(ushort4_t*)&so[e * 132 + cloc] = r;
        }
    }
    __syncthreads();

    // write this (box, channel-half): 128*49 f32 contiguous, non-temporal
    float* __restrict__ outn = out + (size_t)n * (NCH * NBIN) + (size_t)chalf * NBIN;
    for (int idx = threadIdx.x; idx < (128 * NBIN) / 4; idx += 256) {
        const int k = idx * 4;
        float4_t r;
        { const int k0 = k;     const int c = k0 / NBIN; r.x = bf2f(so[(k0 - c * NBIN) * 132 + c]); }
        { const int k1 = k + 1; const int c = k1 / NBIN; r.y = bf2f(so[(k1 - c * NBIN) * 132 + c]); }
        { const int k2 = k + 2; const int c = k2 / NBIN; r.z = bf2f(so[(k2 - c * NBIN) * 132 + c]); }
        { const int k3 = k + 3; const int c = k3 / NBIN; r.w = bf2f(so[(k3 - c * NBIN) * 132 + c]); }
        __builtin_nontemporal_store(r, (float4_t*)outn + idx);
    }
}

// ---------------- fallback (round-1 kernel) if ws too small ----------------
__global__ __launch_bounds__(256) void pooler_kernel(
    const float* __restrict__ f0, const float* __restrict__ f1,
    const float* __restrict__ f2, const float* __restrict__ f3,
    const float* __restrict__ boxes, const int* __restrict__ bidx,
    float* __restrict__ out, int nbox)
{
    const int n = blockIdx.x;
    if (n >= nbox) return;
    const int c = threadIdx.x;

    const float bx1 = boxes[4*n+0];
    const float by1 = boxes[4*n+1];
    const float bx2 = boxes[4*n+2];
    const float by2 = boxes[4*n+3];

    const float ww = bx2 - bx1 + 1.0f;
    const float hh = by2 - by1 + 1.0f;
    const float s  = sqrtf(ww * hh);
    int lvl = (int)floorf(4.0f + log2f(1e-6f + s * (1.0f / 224.0f)));
    lvl = min(max(lvl, 2), 5) - 2;

    const float* f;
    int H, W;
    float scale;
    if (lvl == 0)      { f = f0; H = 200; W = 304; scale = 0.25f;    }
    else if (lvl == 1) { f = f1; H = 100; W = 152; scale = 0.125f;   }
    else if (lvl == 2) { f = f2; H = 50;  W = 76;  scale = 0.0625f;  }
    else               { f = f3; H = 25;  W = 38;  scale = 0.03125f; }

    const int b = bidx[n];
    const float* __restrict__ fb = f + ((size_t)b * NCH + c) * (size_t)(H * W);

    const float x1 = bx1 * scale;
    const float y1 = by1 * scale;
    const float x2 = bx2 * scale;
    const float y2 = by2 * scale;
    const float roi_w = fmaxf(x2 - x1, 1.0f);
    const float roi_h = fmaxf(y2 - y1, 1.0f);
    const float bw = roi_w * (1.0f / NOUT);
    const float bh = roi_h * (1.0f / NOUT);

    const float Hf = (float)H, Wf = (float)W;
    float* __restrict__ outc = out + ((size_t)n * NCH + c) * NBIN;

    for (int py = 0; py < NOUT; ++py) {
        for (int px = 0; px < NOUT; ++px) {
            float acc = 0.0f;
            #pragma unroll
            for (int iy = 0; iy < 2; ++iy) {
                #pragma unroll
                for (int ix = 0; ix < 2; ++ix) {
                    float y = y1 + ((float)py + 0.25f + 0.5f * (float)iy) * bh;
                    float x = x1 + ((float)px + 0.25f + 0.5f * (float)ix) * bw;
                    const bool valid = (y >= -1.0f) && (y <= Hf) && (x >= -1.0f) && (x <= Wf);
                    y = fminf(fmaxf(y, 0.0f), Hf - 1.0f);
                    x = fminf(fmaxf(x, 0.0f), Wf - 1.0f);
                    const int y0 = (int)floorf(y);
                    const int x0 = (int)floorf(x);
                    const int y1i = min(y0 + 1, H - 1);
                    const int x1i = min(x0 + 1, W - 1);
                    const float ly = y - (float)y0;
                    const float lx = x - (float)x0;
                    const float hy = 1.0f - ly;
                    const float hx = 1.0f - lx;
                    const float v00 = fb[y0  * W + x0 ];
                    const float v01 = fb[y0  * W + x1i];
                    const float v10 = fb[y1i * W + x0 ];
                    const float v11 = fb[y1i * W + x1i];
                    float v = hy * hx * v00 + hy * lx * v01
                            + ly * hx * v10 + ly * lx * v11;
                    acc += valid ? v : 0.0f;
                }
            }
            outc[py * NOUT + px] = acc * 0.25f;
        }
    }
}

extern "C" void kernel_launch(void* const* d_in, const int* in_sizes, int n_in,
                              void* d_out, int out_size, void* d_ws, size_t ws_size,
                              hipStream_t stream) {
    const float* f0    = (const float*)d_in[0];
    const float* f1    = (const float*)d_in[1];
    const float* f2    = (const float*)d_in[2];
    const float* f3    = (const float*)d_in[3];
    const float* boxes = (const float*)d_in[4];
    const int*   bidx  = (const int*)d_in[5];
    float*       out   = (float*)d_out;

    const int nbox = in_sizes[5];

    const size_t NEED = 41344000ull * sizeof(unsigned short);  // 82.7 MB
    if (ws_size >= NEED) {
        unsigned short* t = (unsigned short*)d_ws;
        transpose_all_kernel<<<10104, 256, 0, stream>>>(f0, f1, f2, f3, t);
        pool_nhwc_kernel<<<dim3(nbox, 2), 256, 0, stream>>>(t, boxes, bidx, out, nbox);
    } else {
        pooler_kernel<<<nbox, 256, 0, stream>>>(f0, f1, f2, f3, boxes, bidx, out, nbox);
    }
}

// Round 13
// 75.116 us; speedup vs baseline: 1.0893x; 1.0765x over previous
//
#include <hip/hip_runtime.h>
#include <hip/hip_bf16.h>

#define NOUT 7
#define NBIN 49
#define NCH 256

typedef unsigned short ushort4_t __attribute__((ext_vector_type(4)));
typedef float float4_t __attribute__((ext_vector_type(4)));

__device__ inline float bflo(unsigned int u) { return __uint_as_float(u << 16); }
__device__ inline float bfhi(unsigned int u) { return __uint_as_float(u & 0xffff0000u); }
__device__ inline float bf2f(unsigned short u) { return __uint_as_float(((unsigned int)u) << 16); }
__device__ inline unsigned short f2bf(float f) {
    __hip_bfloat16 h = __float2bfloat16(f);
    return *reinterpret_cast<unsigned short*>(&h);
}

// ---------- merged NCHW f32 -> NHWC bf16 transpose (R10 config: best measured) ----------
// Conflict-free [64][65] scalar-LDS body, dense-sibling dispatch order
// (bid = ptile*8 + (b*4 + ctile)). Plain (cached) input loads: L3 serves ~half
// the input re-reads across replays — measured faster than nt bypass (R12).
// level block counts: l0 950*8=7600, l1 238*8=1904, l2 60*8=480, l3 15*8=120 => 10104
__global__ __launch_bounds__(256) void transpose_all_kernel(
    const float* __restrict__ f0, const float* __restrict__ f1,
    const float* __restrict__ f2, const float* __restrict__ f3,
    unsigned short* __restrict__ ws)
{
    __shared__ float tile[64][65];   // stride 65: writes stride-1, reads conflict-free

    int bid = blockIdx.x;
    const float* in;
    unsigned short* out;
    int HW;
    if (bid < 7600)      { in = f0; out = ws;            HW = 60800; }
    else if (bid < 9504) { in = f1; out = ws + 31129600; HW = 15200; bid -= 7600; }
    else if (bid < 9984) { in = f2; out = ws + 38912000; HW = 3800;  bid -= 9504; }
    else                 { in = f3; out = ws + 40857600; HW = 950;   bid -= 9984; }

    const int combo = bid & 7;         // dense-sibling: combo is the FAST index
    const int p0    = (bid >> 3) << 6;
    const int c0    = (combo & 3) << 6;
    const int b     = combo >> 2;

    const int tp = threadIdx.x & 63;   // p lane (coalesced 256B reads)
    const int tq = threadIdx.x >> 6;   // wave id

    const size_t inb = (size_t)b * NCH * (size_t)HW;
    if (p0 + tp < HW) {
        #pragma unroll
        for (int cc = 0; cc < 64; cc += 4)
            tile[cc + tq][tp] = in[inb + (size_t)(c0 + cc + tq) * HW + (p0 + tp)];
    }
    __syncthreads();

    const size_t outb = (size_t)b * (size_t)HW * NCH;
    const int cl = (tp & 31) * 2;        // channel pair
    const int pr = tq * 2 + (tp >> 5);   // p row within each group of 8
    #pragma unroll
    for (int pp = 0; pp < 64; pp += 8) {
        const int p = p0 + pp + pr;
        if (p < HW) {
            __hip_bfloat162 v;
            v.x = __float2bfloat16(tile[cl][pp + pr]);
            v.y = __float2bfloat16(tile[cl + 1][pp + pr]);
            *(__hip_bfloat162*)(out + outb + (size_t)p * NCH + (c0 + cl)) = v;
        }
    }
}

// ---------- pooling from NHWC bf16: 2 blocks/box (128 ch), 2 bins/wave, nt stores ----------
__global__ __launch_bounds__(256) void pool_nhwc_kernel(
    const unsigned short* __restrict__ ws, const float* __restrict__ boxes,
    const int* __restrict__ bidx, float* __restrict__ out, int nbox)
{
    __shared__ unsigned short so[NBIN * 132];   // [bin][c_local], bf16, 12.9 KB

    const int n = blockIdx.x;
    if (n >= nbox) return;
    const int chalf = blockIdx.y << 7;          // 0 or 128
    const int lane = threadIdx.x & 63;
    const int wave = threadIdx.x >> 6;

    const float bx1 = boxes[4*n+0];
    const float by1 = boxes[4*n+1];
    const float bx2 = boxes[4*n+2];
    const float by2 = boxes[4*n+3];

    const float wwb = bx2 - bx1 + 1.0f;
    const float hhb = by2 - by1 + 1.0f;
    const float s  = sqrtf(wwb * hhb);
    int lvl = (int)floorf(4.0f + log2f(1e-6f + s * (1.0f / 224.0f)));
    lvl = min(max(lvl, 2), 5) - 2;

    int H, W;
    float scale;
    size_t off;
    if (lvl == 0)      { H = 200; W = 304; scale = 0.25f;    off = 0;        }
    else if (lvl == 1) { H = 100; W = 152; scale = 0.125f;   off = 31129600; }
    else if (lvl == 2) { H = 50;  W = 76;  scale = 0.0625f;  off = 38912000; }
    else               { H = 25;  W = 38;  scale = 0.03125f; off = 40857600; }

    const int b = bidx[n];
    const int cloc = (lane & 31) * 4;           // local channel (0..124)
    const unsigned short* __restrict__ fb =
        ws + off + (size_t)b * (size_t)(H * W) * NCH + chalf + cloc;

    const float x1 = bx1 * scale;
    const float y1 = by1 * scale;
    const float x2 = bx2 * scale;
    const float y2 = by2 * scale;
    const float roi_w = fmaxf(x2 - x1, 1.0f);
    const float roi_h = fmaxf(y2 - y1, 1.0f);
    const float bw = roi_w * (1.0f / NOUT);
    const float bh = roi_h * (1.0f / NOUT);

    const float Hf = (float)H, Wf = (float)W;

    // wave w covers bin pairs {2w, 2w+1} stepping by 8; half-wave picks the pair element
    for (int eb = wave * 2; eb < NBIN; eb += 8) {
        const int e = eb + (lane >> 5);
        const bool evalid = (e < NBIN);
        const int ec = evalid ? e : 0;
        const int py = ec / NOUT;
        const int px = ec - py * NOUT;
        float a0 = 0.0f, a1 = 0.0f, a2 = 0.0f, a3 = 0.0f;
        #pragma unroll
        for (int iy = 0; iy < 2; ++iy) {
            #pragma unroll
            for (int ix = 0; ix < 2; ++ix) {
                float y = y1 + ((float)py + 0.25f + 0.5f * (float)iy) * bh;
                float x = x1 + ((float)px + 0.25f + 0.5f * (float)ix) * bw;
                const bool valid = (y >= -1.0f) && (y <= Hf) && (x >= -1.0f) && (x <= Wf);
                y = fminf(fmaxf(y, 0.0f), Hf - 1.0f);
                x = fminf(fmaxf(x, 0.0f), Wf - 1.0f);
                const int y0 = (int)floorf(y);
                const int x0 = (int)floorf(x);
                const int y1i = min(y0 + 1, H - 1);
                const int x1i = min(x0 + 1, W - 1);
                const float ly = y - (float)y0;
                const float lx = x - (float)x0;
                const float hy = 1.0f - ly;
                const float hx = 1.0f - lx;
                const float w00 = hy * hx, w01 = hy * lx, w10 = ly * hx, w11 = ly * lx;

                const uint2 u00 = *(const uint2*)(fb + (unsigned)(y0  * W + x0 ) * NCH);
                const uint2 u01 = *(const uint2*)(fb + (unsigned)(y0  * W + x1i) * NCH);
                const uint2 u10 = *(const uint2*)(fb + (unsigned)(y1i * W + x0 ) * NCH);
                const uint2 u11 = *(const uint2*)(fb + (unsigned)(y1i * W + x1i) * NCH);

                if (valid) {
                    a0 += w00 * bflo(u00.x) + w01 * bflo(u01.x) + w10 * bflo(u10.x) + w11 * bflo(u11.x);
                    a1 += w00 * bfhi(u00.x) + w01 * bfhi(u01.x) + w10 * bfhi(u10.x) + w11 * bfhi(u11.x);
                    a2 += w00 * bflo(u00.y) + w01 * bflo(u01.y) + w10 * bflo(u10.y) + w11 * bflo(u11.y);
                    a3 += w00 * bfhi(u00.y) + w01 * bfhi(u01.y) + w10 * bfhi(u10.y) + w11 * bfhi(u11.y);
                }
            }
        }
        if (evalid) {
            ushort4_t r;
            r[0] = f2bf(a0 * 0.25f);
            r[1] = f2bf(a1 * 0.25f);
            r[2] = f2bf(a2 * 0.25f);
            r[3] = f2bf(a3 * 0.25f);
            *(ushort4_t*)&so[e * 132 + cloc] = r;
        }
    }
    __syncthreads();

    // write this (box, channel-half): 128*49 f32 contiguous, non-temporal
    float* __restrict__ outn = out + (size_t)n * (NCH * NBIN) + (size_t)chalf * NBIN;
    for (int idx = threadIdx.x; idx < (128 * NBIN) / 4; idx += 256) {
        const int k = idx * 4;
        float4_t r;
        { const int k0 = k;     const int c = k0 / NBIN; r.x = bf2f(so[(k0 - c * NBIN) * 132 + c]); }
        { const int k1 = k + 1; const int c = k1 / NBIN; r.y = bf2f(so[(k1 - c * NBIN) * 132 + c]); }
        { const int k2 = k + 2; const int c = k2 / NBIN; r.z = bf2f(so[(k2 - c * NBIN) * 132 + c]); }
        { const int k3 = k + 3; const int c = k3 / NBIN; r.w = bf2f(so[(k3 - c * NBIN) * 132 + c]); }
        __builtin_nontemporal_store(r, (float4_t*)outn + idx);
    }
}

// ---------------- fallback (round-1 kernel) if ws too small ----------------
__global__ __launch_bounds__(256) void pooler_kernel(
    const float* __restrict__ f0, const float* __restrict__ f1,
    const float* __restrict__ f2, const float* __restrict__ f3,
    const float* __restrict__ boxes, const int* __restrict__ bidx,
    float* __restrict__ out, int nbox)
{
    const int n = blockIdx.x;
    if (n >= nbox) return;
    const int c = threadIdx.x;

    const float bx1 = boxes[4*n+0];
    const float by1 = boxes[4*n+1];
    const float bx2 = boxes[4*n+2];
    const float by2 = boxes[4*n+3];

    const float ww = bx2 - bx1 + 1.0f;
    const float hh = by2 - by1 + 1.0f;
    const float s  = sqrtf(ww * hh);
    int lvl = (int)floorf(4.0f + log2f(1e-6f + s * (1.0f / 224.0f)));
    lvl = min(max(lvl, 2), 5) - 2;

    const float* f;
    int H, W;
    float scale;
    if (lvl == 0)      { f = f0; H = 200; W = 304; scale = 0.25f;    }
    else if (lvl == 1) { f = f1; H = 100; W = 152; scale = 0.125f;   }
    else if (lvl == 2) { f = f2; H = 50;  W = 76;  scale = 0.0625f;  }
    else               { f = f3; H = 25;  W = 38;  scale = 0.03125f; }

    const int b = bidx[n];
    const float* __restrict__ fb = f + ((size_t)b * NCH + c) * (size_t)(H * W);

    const float x1 = bx1 * scale;
    const float y1 = by1 * scale;
    const float x2 = bx2 * scale;
    const float y2 = by2 * scale;
    const float roi_w = fmaxf(x2 - x1, 1.0f);
    const float roi_h = fmaxf(y2 - y1, 1.0f);
    const float bw = roi_w * (1.0f / NOUT);
    const float bh = roi_h * (1.0f / NOUT);

    const float Hf = (float)H, Wf = (float)W;
    float* __restrict__ outc = out + ((size_t)n * NCH + c) * NBIN;

    for (int py = 0; py < NOUT; ++py) {
        for (int px = 0; px < NOUT; ++px) {
            float acc = 0.0f;
            #pragma unroll
            for (int iy = 0; iy < 2; ++iy) {
                #pragma unroll
                for (int ix = 0; ix < 2; ++ix) {
                    float y = y1 + ((float)py + 0.25f + 0.5f * (float)iy) * bh;
                    float x = x1 + ((float)px + 0.25f + 0.5f * (float)ix) * bw;
                    const bool valid = (y >= -1.0f) && (y <= Hf) && (x >= -1.0f) && (x <= Wf);
                    y = fminf(fmaxf(y, 0.0f), Hf - 1.0f);
                    x = fminf(fmaxf(x, 0.0f), Wf - 1.0f);
                    const int y0 = (int)floorf(y);
                    const int x0 = (int)floorf(x);
                    const int y1i = min(y0 + 1, H - 1);
                    const int x1i = min(x0 + 1, W - 1);
                    const float ly = y - (float)y0;
                    const float lx = x - (float)x0;
                    const float hy = 1.0f - ly;
                    const float hx = 1.0f - lx;
                    const float v00 = fb[y0  * W + x0 ];
                    const float v01 = fb[y0  * W + x1i];
                    const float v10 = fb[y1i * W + x0 ];
                    const float v11 = fb[y1i * W + x1i];
                    float v = hy * hx * v00 + hy * lx * v01
                            + ly * hx * v10 + ly * lx * v11;
                    acc += valid ? v : 0.0f;
                }
            }
            outc[py * NOUT + px] = acc * 0.25f;
        }
    }
}

extern "C" void kernel_launch(void* const* d_in, const int* in_sizes, int n_in,
                              void* d_out, int out_size, void* d_ws, size_t ws_size,
                              hipStream_t stream) {
    const float* f0    = (const float*)d_in[0];
    const float* f1    = (const float*)d_in[1];
    const float* f2    = (const float*)d_in[2];
    const float* f3    = (const float*)d_in[3];
    const float* boxes = (const float*)d_in[4];
    const int*   bidx  = (const int*)d_in[5];
    float*       out   = (float*)d_out;

    const int nbox = in_sizes[5];

    const size_t NEED = 41344000ull * sizeof(unsigned short);  // 82.7 MB
    if (ws_size >= NEED) {
        unsigned short* t = (unsigned short*)d_ws;
        transpose_all_kernel<<<10104, 256, 0, stream>>>(f0, f1, f2, f3, t);
        pool_nhwc_kernel<<<dim3(nbox, 2), 256, 0, stream>>>(t, boxes, bidx, out, nbox);
    } else {
        pooler_kernel<<<nbox, 256, 0, stream>>>(f0, f1, f2, f3, boxes, bidx, out, nbox);
    }
}